// Round 3
// baseline (155.878 us; speedup 1.0000x reference)
//
#include <hip/hip_runtime.h>
#include <hip/hip_bf16.h>

// GraphAttentionLayer on MI355X. fp32 I/O, bf16 MFMA internally.
// e[b,i,j] = leakyrelu(s1_i + s2_j), softmax over j, out = elu(attn @ Wh).
// NaN-proof factorization with M2 = max_j s2_j:
//   x_i = s1_i + M2; m_i = max(x_i, ALPHA*x_i)  (row max of e, LR monotone)
//   p_ij = max(Ar_i*E_j, Br_i*F_j), all four factors <= 1:
//   Ar = exp(x-m), Br = exp(ALPHA*x-m), E = exp(s2-M2), F = exp(ALPHA*(s2-M2)).
// K1: WhT bf16 + s1,s2 + per-block max(s2).  K2: M2 + E/F tables.
// K3: MFMA P@Wh with P generated in-register in A-frag layout; fused softmax
//     normalize + ELU epilogue. 64KB LDS double buffer, global_load_lds w=16.

#define ALPHA 0.2f
#define NN 4096
#define FD 128

typedef __attribute__((ext_vector_type(8))) short s8v;     // 8 x bf16 (raw bits)
typedef __attribute__((ext_vector_type(4))) float f4v;     // MFMA C/D

__device__ __forceinline__ unsigned short f2bf(float x) {  // RNE float->bf16
  unsigned u = __float_as_uint(x);
  u += 0x7FFFu + ((u >> 16) & 1u);
  return (unsigned short)(u >> 16);
}
__device__ __forceinline__ void gl2lds16(const void* g, void* l) {
  __builtin_amdgcn_global_load_lds(
      (const __attribute__((address_space(1))) unsigned int*)g,
      (__attribute__((address_space(3))) unsigned int*)l, 16, 0, 0);
}

// ---------------- K1: WhT + s1 + s2 + per-block max(s2) ----------------
// grid 128 blocks x 256 thr. block: b = blk>>5, j-tile of 128 nodes.
// MFMA: C[m=f][n=j] = sum_i W^T[f][i] * h[j][i].
__global__ __launch_bounds__(256, 2) void k1_gemm(
    const float* __restrict__ h,            // [4][4096][128] f32
    const float* __restrict__ W,            // [128][128] f32
    const float* __restrict__ a,            // [256] f32
    unsigned short* __restrict__ WhT,       // [4][128][4096] bf16
    float* __restrict__ s1g,                // [4][4096]
    float* __restrict__ s2g,                // [4][4096]
    float* __restrict__ blockmax)           // [128]
{
  __shared__ __align__(16) unsigned char wt_ls[32768]; // W^T bf16, xor-swizzled
  __shared__ float wred[4];
  const int tid = threadIdx.x;
  const int b = blockIdx.x >> 5;
  const int j0 = (blockIdx.x & 31) << 7;

  // stage W^T (bf16): elem (i,f) -> byte f*256 + ((i>>3)^(f&15))*16 + (i&7)*2
  for (int it = 0; it < 16; ++it) {
    int cidx = it * 256 + tid;                 // 4096 chunks of 4 floats
    int i = cidx >> 5;                         // 32 chunks per 128-elem row
    int f0 = (cidx & 31) << 2;
    f4v v = *(const f4v*)(W + (size_t)cidx * 4);
#pragma unroll
    for (int e = 0; e < 4; ++e) {
      int f = f0 + e;
      int byte = f * 256 + (((i >> 3) ^ (f & 15)) << 4) + ((i & 7) << 1);
      *(unsigned short*)(wt_ls + byte) = f2bf(v[e]);
    }
  }
  __syncthreads();

  const int w = tid >> 6, lane = tid & 63;
  const int quad = lane >> 4, lcol = lane & 15;

  f4v acc[8][2];
#pragma unroll
  for (int mt = 0; mt < 8; ++mt)
#pragma unroll
    for (int nl = 0; nl < 2; ++nl) acc[mt][nl] = (f4v){0.f, 0.f, 0.f, 0.f};

#pragma unroll
  for (int kk = 0; kk < 4; ++kk) {         // K=128, 4 steps of 32
    s8v af[8];
#pragma unroll
    for (int mt = 0; mt < 8; ++mt) {       // A = W^T[f][i], m = 16mt + lcol
      int m = 16 * mt + lcol;
      int byte = m * 256 + ((((kk << 2) + quad) ^ (m & 15)) << 4);
      af[mt] = *(const s8v*)(wt_ls + byte);
    }
    s8v bfr[2];
#pragma unroll
    for (int nl = 0; nl < 2; ++nl) {       // B = h[j][i] (8 consecutive i)
      int jl = ((2 * w + nl) << 4) + lcol;
      size_t elem = (((size_t)b * NN + j0 + jl) << 7) + (kk << 5) + (quad << 3);
      f4v v0 = *(const f4v*)(h + elem);
      f4v v1 = *(const f4v*)(h + elem + 4);
      s8v bb;
#pragma unroll
      for (int e = 0; e < 4; ++e) {
        bb[e] = (short)f2bf(v0[e]);
        bb[4 + e] = (short)f2bf(v1[e]);
      }
      bfr[nl] = bb;
    }
#pragma unroll
    for (int mt = 0; mt < 8; ++mt)
#pragma unroll
      for (int nl = 0; nl < 2; ++nl)
        acc[mt][nl] = __builtin_amdgcn_mfma_f32_16x16x32_bf16(af[mt], bfr[nl], acc[mt][nl], 0, 0, 0);
  }

  // epilogue: s1/s2 dots from fp32 acc; store WhT bf16
  float s1p0 = 0.f, s1p1 = 0.f, s2p0 = 0.f, s2p1 = 0.f;
#pragma unroll
  for (int mt = 0; mt < 8; ++mt)
#pragma unroll
    for (int r = 0; r < 4; ++r) {
      int f = 16 * mt + 4 * quad + r;      // C row = f
      float a1v = a[f];
      float a2v = a[128 + f];
      s1p0 += acc[mt][0][r] * a1v;  s1p1 += acc[mt][1][r] * a1v;
      s2p0 += acc[mt][0][r] * a2v;  s2p1 += acc[mt][1][r] * a2v;
    }
  s1p0 += __shfl_xor(s1p0, 16, 64); s1p0 += __shfl_xor(s1p0, 32, 64);
  s1p1 += __shfl_xor(s1p1, 16, 64); s1p1 += __shfl_xor(s1p1, 32, 64);
  s2p0 += __shfl_xor(s2p0, 16, 64); s2p0 += __shfl_xor(s2p0, 32, 64);
  s2p1 += __shfl_xor(s2p1, 16, 64); s2p1 += __shfl_xor(s2p1, 32, 64);

#pragma unroll
  for (int mt = 0; mt < 8; ++mt)
#pragma unroll
    for (int nl = 0; nl < 2; ++nl) {
      int j = j0 + ((2 * w + nl) << 4) + lcol;
#pragma unroll
      for (int r = 0; r < 4; ++r) {
        int f = 16 * mt + 4 * quad + r;
        WhT[(((size_t)b * FD + f) << 12) + j] = f2bf(acc[mt][nl][r]);
      }
    }
  if (quad == 0) {
    int j = j0 + ((2 * w) << 4) + lcol;
    int gi = b * NN + j;
    s1g[gi] = s1p0; s2g[gi] = s2p0;
    j = j0 + ((2 * w + 1) << 4) + lcol;
    gi = b * NN + j;
    s1g[gi] = s1p1; s2g[gi] = s2p1;
  }
  float m2 = fmaxf(s2p0, s2p1);
#pragma unroll
  for (int d = 1; d < 64; d <<= 1) m2 = fmaxf(m2, __shfl_xor(m2, d, 64));
  if (lane == 0) wred[w] = m2;
  __syncthreads();
  if (tid == 0)
    blockmax[blockIdx.x] = fmaxf(fmaxf(wred[0], wred[1]), fmaxf(wred[2], wred[3]));
}

// ---------------- K2: M2 per batch + E/F tables ----------------
// grid 64 blocks x 256 thr, one element each.
__global__ __launch_bounds__(256) void k2_ef(
    const float* __restrict__ s2g,
    const float* __restrict__ blockmax,
    float* __restrict__ Eg, float* __restrict__ Fg,
    float* __restrict__ M2f)
{
  int gid = blockIdx.x * 256 + threadIdx.x;
  int b = gid >> 12;
  const float* bm = blockmax + b * 32;
  float m = bm[0];
#pragma unroll
  for (int t = 1; t < 32; ++t) m = fmaxf(m, bm[t]);
  float s2 = s2g[gid];
  Eg[gid] = __expf(s2 - m);
  Fg[gid] = __expf(ALPHA * (s2 - m));
  if ((gid & (NN - 1)) == 0) M2f[b] = m;
}

// ---------------- K3: fused softmax + P@Wh + ELU ----------------
// grid 256 blocks x 512 thr (8 waves). block: b = blk>>6, 64-row i-tile.
// wave w: g=w>>2 owns i-rows [32g,32g+32) (mt in {0,1}); kp=w&3 owns
// j-local [32kp,32kp+32) of each 128-j chunk. 32 chunks.
__global__ __launch_bounds__(512, 1) void k3_attn(
    const unsigned short* __restrict__ WhT,
    const float* __restrict__ s1g,
    const float* __restrict__ Eg,
    const float* __restrict__ Fg,
    const float* __restrict__ M2f,
    float* __restrict__ out)
{
  __shared__ __align__(16) unsigned char smem[65536];  // 2 x 32KB WhT tiles
  const int tid = threadIdx.x;
  const int w = tid >> 6, lane = tid & 63;
  const int quad = lane >> 4, lcol = lane & 15;
  const int g = w >> 2, kp = w & 3;
  const int b = blockIdx.x >> 6;
  const int i0 = (blockIdx.x & 63) << 6;

  const float M2 = M2f[b];
  float Ar[2], Br[2];
#pragma unroll
  for (int mt = 0; mt < 2; ++mt) {
    float x = s1g[b * NN + i0 + 32 * g + 16 * mt + lcol] + M2;
    float m = fmaxf(x, ALPHA * x);         // row max of e
    Ar[mt] = __expf(x - m);                // <= 1
    Br[mt] = __expf(ALPHA * x - m);        // <= 1
  }

  f4v acc[2][8];
#pragma unroll
  for (int mt = 0; mt < 2; ++mt)
#pragma unroll
    for (int nt = 0; nt < 8; ++nt) acc[mt][nt] = (f4v){0.f, 0.f, 0.f, 0.f};
  float ls[2] = {0.f, 0.f};

  const unsigned short* whtb = WhT + ((size_t)b * FD << 12);
  const float* Egb = Eg + b * NN;
  const float* Fgb = Fg + b * NN;

  // WhT tile: 128 rows(n=f) x 128 j bf16 = 32KB. Row = 256B = 16 slots of
  // 16B; slot s holds j-octet s^(n&15) (xor swizzle across all 16 slots so
  // compute-side ds_read_b128 spreads over all banks).
  auto stage = [&](int c, int bi) {
    unsigned char* buf = smem + bi * 32768;
    int j0c = c << 7;
#pragma unroll
    for (int t = 0; t < 4; ++t) {
      int cid = t * 512 + tid;             // 2048 chunks of 16B
      int n = cid >> 4;
      int s = cid & 15;
      int oct = s ^ (n & 15);
      gl2lds16(whtb + (((size_t)n) << 12) + j0c + (oct << 3), buf + cid * 16);
    }
  };

  stage(0, 0);
  for (int c = 0; c < 32; ++c) {           // 32 chunks x 128 j
    __syncthreads();                       // chunk c landed (vmcnt drained)
    if (c < 31) stage(c + 1, (c + 1) & 1); // prefetch into other buffer
    unsigned char* buf = smem + (c & 1) * 32768;

    int jg = (c << 7) + (kp << 5) + (quad << 3);
    f4v Ev0 = *(const f4v*)(Egb + jg);
    f4v Ev1 = *(const f4v*)(Egb + jg + 4);
    f4v Fv0 = *(const f4v*)(Fgb + jg);
    f4v Fv1 = *(const f4v*)(Fgb + jg + 4);
    float Ev[8] = {Ev0[0], Ev0[1], Ev0[2], Ev0[3], Ev1[0], Ev1[1], Ev1[2], Ev1[3]};
    float Fv[8] = {Fv0[0], Fv0[1], Fv0[2], Fv0[3], Fv1[0], Fv1[1], Fv1[2], Fv1[3]};

    s8v af[2];
#pragma unroll
    for (int mt = 0; mt < 2; ++mt) {       // P in A-frag layout
      float A = Ar[mt], Bc = Br[mt];
      float lacc = 0.f;
#pragma unroll
      for (int t = 0; t < 8; ++t) {
        float p = fmaxf(A * Ev[t], Bc * Fv[t]);
        lacc += p;
        af[mt][t] = (short)f2bf(p);
      }
      ls[mt] += lacc;
    }
    s8v bfr[8];
    const int oct = (kp << 2) + quad;      // j-octet this lane consumes
#pragma unroll
    for (int nt = 0; nt < 8; ++nt) {       // B = WhT[f][j] from swizzled LDS
      int n = (nt << 4) + lcol;
      int slot = oct ^ (n & 15);
      bfr[nt] = *(const s8v*)(buf + (n << 8) + (slot << 4));
    }
#pragma unroll
    for (int mt = 0; mt < 2; ++mt)
#pragma unroll
      for (int nt = 0; nt < 8; ++nt)
        acc[mt][nt] = __builtin_amdgcn_mfma_f32_16x16x32_bf16(af[mt], bfr[nt], acc[mt][nt], 0, 0, 0);
  }

  // ---- epilogue (overlays smem; all tile reads are behind the barrier) ----
  float* hsum = (float*)smem;              // [64][128] f32 = 32KB
  float* l_red = (float*)(smem + 32768);   // [64]
  __syncthreads();
#pragma unroll
  for (int t = 0; t < 4; ++t)
    *(f4v*)(hsum + tid * 16 + t * 4) = (f4v){0.f, 0.f, 0.f, 0.f};
  if (tid < 64) l_red[tid] = 0.f;
  __syncthreads();

#pragma unroll
  for (int mt = 0; mt < 2; ++mt) {
    float s = ls[mt];
    s += __shfl_xor(s, 16, 64); s += __shfl_xor(s, 32, 64);
    if (quad == 0) atomicAdd(&l_red[32 * g + 16 * mt + lcol], s);
  }
#pragma unroll
  for (int mt = 0; mt < 2; ++mt)
#pragma unroll
    for (int nt = 0; nt < 8; ++nt)
#pragma unroll
      for (int r = 0; r < 4; ++r) {
        int row = 32 * g + 16 * mt + 4 * quad + r;
        int f = (nt << 4) + lcol;
        atomicAdd(&hsum[(row << 7) + f], acc[mt][nt][r]);
      }
  __syncthreads();

  {
    int r = (w << 3) + (lane >> 3);        // 8 rows per wave, 8 lanes per row
    int f0 = (lane & 7) << 4;
    float il = 1.0f / l_red[r];            // l >= 1 by construction
    float ov[16];
#pragma unroll
    for (int t = 0; t < 16; ++t) {
      float v = hsum[(r << 7) + f0 + t] * il;
      ov[t] = v > 0.f ? v : (__expf(v) - 1.f);   // elu
    }
    size_t o = (((size_t)b * NN + i0 + r) << 7) + f0;
#pragma unroll
    for (int t = 0; t < 4; ++t)
      *(f4v*)(out + o + 4 * t) = (f4v){ov[4*t], ov[4*t+1], ov[4*t+2], ov[4*t+3]};
  }
}

extern "C" void kernel_launch(void* const* d_in, const int* in_sizes, int n_in,
                              void* d_out, int out_size, void* d_ws, size_t ws_size,
                              hipStream_t stream) {
  const float* h = (const float*)d_in[0];
  const float* W = (const float*)d_in[1];
  const float* a = (const float*)d_in[2];
  float* out = (float*)d_out;
  unsigned char* ws = (unsigned char*)d_ws;

  // workspace layout
  unsigned short* WhT = (unsigned short*)ws;              // 4 MB bf16
  float* s1g = (float*)(ws + 4194304);                    // 64 KB
  float* s2g = (float*)(ws + 4259840);                    // 64 KB
  float* Eg  = (float*)(ws + 4325376);                    // 64 KB
  float* Fg  = (float*)(ws + 4390912);                    // 64 KB
  float* bmx = (float*)(ws + 4456448);                    // 512 B
  float* M2f = (float*)(ws + 4456960);                    // 16 B
  const size_t NEEDED = 4456976;
  if (ws_size < NEEDED) return;  // diagnostic: clean absmax fail => ws too small

  hipLaunchKernelGGL(k1_gemm, dim3(128), dim3(256), 0, stream,
                     h, W, a, WhT, s1g, s2g, bmx);
  hipLaunchKernelGGL(k2_ef, dim3(64), dim3(256), 0, stream,
                     s2g, bmx, Eg, Fg, M2f);
  hipLaunchKernelGGL(k3_attn, dim3(256), dim3(512), 0, stream,
                     WhT, s1g, Eg, Fg, M2f, out);
}

// Round 4
// 147.808 us; speedup vs baseline: 1.0546x; 1.0546x over previous
//
#include <hip/hip_runtime.h>
#include <hip/hip_bf16.h>

// GraphAttentionLayer on MI355X. fp32 I/O, bf16 MFMA internally.
// e[b,i,j] = leakyrelu(s1_i + s2_j), softmax over j, out = elu(attn @ Wh).
// p_ij = max(Ar_i*E_j, Br_i*F_j) with all factors <= 1 (M2 = max_j s2_j).
// K0: bf16 swizzled W^T image.  K1: WhT bf16 + s1,s2 + blockmax.
// K2: M2 + E/F tables.  K3: P@Wh with P generated in A-frag layout, l via
// ones-column MFMA (consistent with bf16 p-hat), fused softmax+ELU epilogue.

#define ALPHA 0.2f
#define NN 4096
#define FD 128

typedef __attribute__((ext_vector_type(8))) short s8v;     // 8 x bf16 raw bits
typedef __attribute__((ext_vector_type(4))) float f4v;     // MFMA C/D
typedef __attribute__((ext_vector_type(2))) unsigned int u2v;

__device__ __forceinline__ unsigned short f2bf(float x) {  // RNE float->bf16
  unsigned u = __float_as_uint(x);
  u += 0x7FFFu + ((u >> 16) & 1u);
  return (unsigned short)(u >> 16);
}
__device__ __forceinline__ void gl2lds16(const void* g, void* l) {
  __builtin_amdgcn_global_load_lds(
      (const __attribute__((address_space(1))) unsigned int*)g,
      (__attribute__((address_space(3))) unsigned int*)l, 16, 0, 0);
}

// ---------------- K0: swizzled bf16 W^T image in ws ----------------
// (f,i) -> byte f*256 + (((i>>3)^(f&15))<<4) + (i&7)*2.  16 blocks x 256 thr.
__global__ __launch_bounds__(256) void k0_prep(
    const float* __restrict__ W,            // [128][128] f32, W[i][f]
    unsigned short* __restrict__ WTsw)      // 32768 B image
{
  int cidx = blockIdx.x * 256 + threadIdx.x;   // 4096 chunks of 4 floats
  int i = cidx >> 5;
  int f0 = (cidx & 31) << 2;
  f4v v = *(const f4v*)(W + (size_t)cidx * 4);
#pragma unroll
  for (int e = 0; e < 4; ++e) {
    int f = f0 + e;
    int byte = f * 256 + ((((i >> 3) ^ (f & 15))) << 4) + ((i & 7) << 1);
    WTsw[byte >> 1] = f2bf(v[e]);
  }
}

// ---------------- K1: WhT + s1 + s2 + per-block max(s2) ----------------
// grid 256 x 256 thr (4 waves). b = blk>>6, j0 = (blk&63)<<6, wave w: 16 j.
// MFMA roles: C[m=j][n=f] = sum_i h[j][i] * W^T[f][i].
__global__ __launch_bounds__(256, 4) void k1_gemm(
    const float* __restrict__ h,            // [4][4096][128] f32
    const unsigned short* __restrict__ WTsw,
    const float* __restrict__ a,            // [256] f32
    unsigned short* __restrict__ WhT,       // [4][128][4096] bf16
    float* __restrict__ s1g,                // [4][4096]
    float* __restrict__ s2g,                // [4][4096]
    float* __restrict__ blockmax)           // [256]
{
  __shared__ __align__(16) unsigned char wls[32768];
  __shared__ float wred[4];
  const int tid = threadIdx.x;
  const int b = blockIdx.x >> 6;
  const int j0 = (blockIdx.x & 63) << 6;

#pragma unroll
  for (int tt = 0; tt < 8; ++tt) {          // stage swizzled image linearly
    int cid = tt * 256 + tid;               // 2048 chunks of 16B
    gl2lds16(WTsw + cid * 8, wls + cid * 16);
  }
  __syncthreads();

  const int w = tid >> 6, lane = tid & 63;
  const int quad = lane >> 4, lcol = lane & 15;
  const int jrow = j0 + 16 * w + lcol;      // A-frag m index

  f4v acc[8];
#pragma unroll
  for (int nt = 0; nt < 8; ++nt) acc[nt] = (f4v){0.f, 0.f, 0.f, 0.f};

#pragma unroll
  for (int kk = 0; kk < 4; ++kk) {
    const float* hp = h + (((size_t)(b * NN + jrow)) << 7) + (kk << 5) + (quad << 3);
    f4v v0 = *(const f4v*)hp;
    f4v v1 = *(const f4v*)(hp + 4);
    s8v af;
#pragma unroll
    for (int e = 0; e < 4; ++e) {
      af[e] = (short)f2bf(v0[e]);
      af[4 + e] = (short)f2bf(v1[e]);
    }
#pragma unroll
    for (int nt = 0; nt < 8; ++nt) {        // B = W^T[f][i] from swizzled LDS
      int f = 16 * nt + lcol;
      int slot = ((kk << 2) + quad) ^ (f & 15);
      s8v bfr = *(const s8v*)(wls + (f << 8) + (slot << 4));
      acc[nt] = __builtin_amdgcn_mfma_f32_16x16x32_bf16(af, bfr, acc[nt], 0, 0, 0);
    }
  }

  // s1/s2: dot over f; lane partials over its 8 f values, reduce over lcol.
  float s1v[4] = {0, 0, 0, 0}, s2v[4] = {0, 0, 0, 0};
#pragma unroll
  for (int nt = 0; nt < 8; ++nt) {
    float a1 = a[16 * nt + lcol];
    float a2 = a[128 + 16 * nt + lcol];
#pragma unroll
    for (int r = 0; r < 4; ++r) {
      s1v[r] += acc[nt][r] * a1;
      s2v[r] += acc[nt][r] * a2;
    }
  }
#pragma unroll
  for (int r = 0; r < 4; ++r) {
#pragma unroll
    for (int d = 1; d < 16; d <<= 1) {
      s1v[r] += __shfl_xor(s1v[r], d, 64);
      s2v[r] += __shfl_xor(s2v[r], d, 64);
    }
  }
  if (lcol == 0) {
    int jb = b * NN + j0 + 16 * w + (quad << 2);
    *(f4v*)(s1g + jb) = (f4v){s1v[0], s1v[1], s1v[2], s1v[3]};
    *(f4v*)(s2g + jb) = (f4v){s2v[0], s2v[1], s2v[2], s2v[3]};
  }

  // WhT store: 4 consecutive j per lane, packed round-half-up, dwordx2.
#pragma unroll
  for (int nt = 0; nt < 8; ++nt) {
    int f = 16 * nt + lcol;
    unsigned u0 = __float_as_uint(acc[nt][0]) + 0x8000u;
    unsigned u1 = __float_as_uint(acc[nt][1]) + 0x8000u;
    unsigned u2 = __float_as_uint(acc[nt][2]) + 0x8000u;
    unsigned u3 = __float_as_uint(acc[nt][3]) + 0x8000u;
    u2v pk;
    pk[0] = (u0 >> 16) | (u1 & 0xFFFF0000u);
    pk[1] = (u2 >> 16) | (u3 & 0xFFFF0000u);
    size_t off = (((size_t)b * FD + f) << 12) + j0 + 16 * w + (quad << 2);
    *(u2v*)(WhT + off) = pk;
  }

  float mv = (lcol == 0)
      ? fmaxf(fmaxf(s2v[0], s2v[1]), fmaxf(s2v[2], s2v[3])) : -1e30f;
#pragma unroll
  for (int d = 1; d < 64; d <<= 1) mv = fmaxf(mv, __shfl_xor(mv, d, 64));
  if (lane == 0) wred[w] = mv;
  __syncthreads();
  if (tid == 0)
    blockmax[blockIdx.x] = fmaxf(fmaxf(wred[0], wred[1]), fmaxf(wred[2], wred[3]));
}

// ---------------- K2: M2 per batch + E/F tables ----------------
__global__ __launch_bounds__(256) void k2_ef(
    const float* __restrict__ s2g,
    const float* __restrict__ blockmax,
    float* __restrict__ Eg, float* __restrict__ Fg,
    float* __restrict__ M2f)
{
  int gid = blockIdx.x * 256 + threadIdx.x;
  int b = gid >> 12;
  const float* bm = blockmax + b * 64;
  float m = bm[0];
#pragma unroll
  for (int t = 1; t < 64; ++t) m = fmaxf(m, bm[t]);
  float s2 = s2g[gid];
  Eg[gid] = __expf(s2 - m);
  Fg[gid] = __expf(ALPHA * (s2 - m));
  if ((gid & (NN - 1)) == 0) M2f[b] = m;
}

// ---------------- K3: fused softmax + P@Wh + ELU ----------------
// grid 256 x 256 thr (4 waves). b = blk>>6, 64-row i-tile. Wave kp owns
// j-local [32kp,32kp+32) of each 128-j chunk; mt=4 row-tiles per wave
// (B-frags read once per byte). l via ones-column MFMA.
__global__ __launch_bounds__(256, 1) void k3_attn(
    const unsigned short* __restrict__ WhT,
    const float* __restrict__ s1g,
    const float* __restrict__ Eg,
    const float* __restrict__ Fg,
    const float* __restrict__ M2f,
    float* __restrict__ out)
{
  __shared__ __align__(16) unsigned char smem[65536];  // 2 x 32KB WhT tiles
  const int tid = threadIdx.x;
  const int kp = tid >> 6, lane = tid & 63;
  const int quad = lane >> 4, lcol = lane & 15;
  const int b = blockIdx.x >> 6;
  const int i0 = (blockIdx.x & 63) << 6;

  const float M2 = M2f[b];
  float Ar[4], Br[4];
#pragma unroll
  for (int mt = 0; mt < 4; ++mt) {
    float x = s1g[b * NN + i0 + 16 * mt + lcol] + M2;
    float m = fmaxf(x, ALPHA * x);          // row max of e (LR monotone)
    Ar[mt] = __expf(x - m);
    Br[mt] = __expf(ALPHA * x - m);
  }

  f4v acc[4][8], accL[4];
#pragma unroll
  for (int mt = 0; mt < 4; ++mt) {
    accL[mt] = (f4v){0.f, 0.f, 0.f, 0.f};
#pragma unroll
    for (int nt = 0; nt < 8; ++nt) acc[mt][nt] = (f4v){0.f, 0.f, 0.f, 0.f};
  }
  s8v ones;
  {
    short o = (lcol == 0) ? (short)0x3F80 : (short)0;  // bf16 1.0 at n==0
#pragma unroll
    for (int t = 0; t < 8; ++t) ones[t] = o;
  }

  const unsigned short* whtb = WhT + ((size_t)b << 19);
  const float* Egb = Eg + b * NN;
  const float* Fgb = Fg + b * NN;

  // tile: 128 f-rows x 128 j bf16 = 32KB; row 256B = 16 slots of 16B;
  // slot s holds j-octet s^(f&15).
  auto stage = [&](int c, int bi) {
    unsigned char* buf = smem + bi * 32768;
    int j0c = c << 7;
#pragma unroll
    for (int tt = 0; tt < 8; ++tt) {
      int cid = tt * 256 + tid;             // 2048 chunks of 16B
      int n = cid >> 4;
      int oct = (cid & 15) ^ (n & 15);
      gl2lds16(whtb + (((size_t)n) << 12) + j0c + (oct << 3), buf + cid * 16);
    }
  };

  f4v Ec0, Ec1, Fc0, Fc1;
  const int jw = (kp << 5) + (quad << 3);   // wave/quad j offset in chunk
  stage(0, 0);
  Ec0 = *(const f4v*)(Egb + jw); Ec1 = *(const f4v*)(Egb + jw + 4);
  Fc0 = *(const f4v*)(Fgb + jw); Fc1 = *(const f4v*)(Fgb + jw + 4);

  for (int c = 0; c < 32; ++c) {            // 32 chunks x 128 j
    __syncthreads();                        // tile c + EF(c) landed
    float Ev[8] = {Ec0[0], Ec0[1], Ec0[2], Ec0[3], Ec1[0], Ec1[1], Ec1[2], Ec1[3]};
    float Fv[8] = {Fc0[0], Fc0[1], Fc0[2], Fc0[3], Fc1[0], Fc1[1], Fc1[2], Fc1[3]};
    if (c < 31) {
      stage(c + 1, (c + 1) & 1);            // prefetch tile
      int jg = ((c + 1) << 7) + jw;         // prefetch E/F into regs
      Ec0 = *(const f4v*)(Egb + jg); Ec1 = *(const f4v*)(Egb + jg + 4);
      Fc0 = *(const f4v*)(Fgb + jg); Fc1 = *(const f4v*)(Fgb + jg + 4);
    }
    unsigned char* buf = smem + (c & 1) * 32768;

    s8v af[4];
#pragma unroll
    for (int mt = 0; mt < 4; ++mt) {        // P in A-frag layout
      float A = Ar[mt], Bc = Br[mt];
#pragma unroll
      for (int t = 0; t < 8; ++t) {
        float p = fmaxf(A * Ev[t], Bc * Fv[t]);
        af[mt][t] = (short)((__float_as_uint(p) + 0x8000u) >> 16);
      }
    }
#pragma unroll
    for (int nt = 0; nt < 8; ++nt) {        // B-frags read ONCE, reused 4x
      int n = (nt << 4) + lcol;
      int slot = ((kp << 2) + quad) ^ (n & 15);
      s8v bfr = *(const s8v*)(buf + (n << 8) + (slot << 4));
#pragma unroll
      for (int mt = 0; mt < 4; ++mt)
        acc[mt][nt] = __builtin_amdgcn_mfma_f32_16x16x32_bf16(af[mt], bfr, acc[mt][nt], 0, 0, 0);
    }
#pragma unroll
    for (int mt = 0; mt < 4; ++mt)          // l = sum_j p-hat (consistent)
      accL[mt] = __builtin_amdgcn_mfma_f32_16x16x32_bf16(af[mt], ones, accL[mt], 0, 0, 0);
  }

  // ---- epilogue: cross-kp reduce in LDS (bank-swizzled), ELU, store ----
  float* hsum = (float*)smem;               // [64][128] f32 swizzled
  float* l_red = (float*)(smem + 32768);    // [64]
  __syncthreads();
#pragma unroll
  for (int t = 0; t < 8; ++t)
    *(f4v*)(hsum + tid * 32 + t * 4) = (f4v){0.f, 0.f, 0.f, 0.f};
  if (tid < 64) l_red[tid] = 0.f;
  __syncthreads();

#pragma unroll
  for (int mt = 0; mt < 4; ++mt) {
    if (lcol == 0) {
#pragma unroll
      for (int r = 0; r < 4; ++r)
        atomicAdd(&l_red[16 * mt + (quad << 2) + r], accL[mt][r]);
    }
#pragma unroll
    for (int nt = 0; nt < 8; ++nt)
#pragma unroll
      for (int r = 0; r < 4; ++r) {
        int row = 16 * mt + (quad << 2) + r;
        int f = (nt << 4) + lcol;
        int fx = (f + (quad << 3)) & 127;   // quad-offset: conflict-free banks
        atomicAdd(&hsum[(row << 7) + fx], acc[mt][nt][r]);
      }
  }
  __syncthreads();

  {
    int r = tid >> 2;                       // 64 rows, 4 thr/row, 32 f each
    int f0 = (tid & 3) << 5;
    int off = ((r >> 2) & 3) << 3;          // same swizzle as writes
    float il = 1.0f / l_red[r];             // l >= 1 by construction
    size_t o = (((size_t)b * NN + i0 + r) << 7) + f0;
#pragma unroll
    for (int t = 0; t < 8; ++t) {
      int fx = (f0 + 4 * t + off) & 127;
      f4v v = *(const f4v*)(hsum + (r << 7) + fx);
      f4v ov;
#pragma unroll
      for (int e = 0; e < 4; ++e) {
        float x = v[e] * il;
        ov[e] = x > 0.f ? x : (__expf(x) - 1.f);  // elu
      }
      *(f4v*)(out + o + 4 * t) = ov;
    }
  }
}

extern "C" void kernel_launch(void* const* d_in, const int* in_sizes, int n_in,
                              void* d_out, int out_size, void* d_ws, size_t ws_size,
                              hipStream_t stream) {
  const float* h = (const float*)d_in[0];
  const float* W = (const float*)d_in[1];
  const float* a = (const float*)d_in[2];
  float* out = (float*)d_out;
  unsigned char* ws = (unsigned char*)d_ws;

  unsigned short* WhT = (unsigned short*)ws;              // 4 MB bf16
  float* s1g = (float*)(ws + 4194304);                    // 64 KB
  float* s2g = (float*)(ws + 4259840);                    // 64 KB
  float* Eg  = (float*)(ws + 4325376);                    // 64 KB
  float* Fg  = (float*)(ws + 4390912);                    // 64 KB
  float* bmx = (float*)(ws + 4456448);                    // 1 KB (256 f32)
  float* M2f = (float*)(ws + 4457472);                    // 16 B
  unsigned short* WTsw = (unsigned short*)(ws + 4457488); // 32 KB image
  const size_t NEEDED = 4457488 + 32768;
  if (ws_size < NEEDED) return;  // clean absmax-fail => ws too small

  hipLaunchKernelGGL(k0_prep, dim3(16), dim3(256), 0, stream, W, WTsw);
  hipLaunchKernelGGL(k1_gemm, dim3(256), dim3(256), 0, stream,
                     h, WTsw, a, WhT, s1g, s2g, bmx);
  hipLaunchKernelGGL(k2_ef, dim3(64), dim3(256), 0, stream,
                     s2g, bmx, Eg, Fg, M2f);
  hipLaunchKernelGGL(k3_attn, dim3(256), dim3(256), 0, stream,
                     WhT, s1g, Eg, Fg, M2f, out);
}